// Round 3
// baseline (288.443 us; speedup 1.0000x reference)
//
#include <hip/hip_runtime.h>
#include <hip/hip_cooperative_groups.h>

namespace cg = cooperative_groups;

#define B_ROWS 4096
#define N_ROWS 8192
#define DDIM   256
#define IT2    2.885390081777927f   /* 1/(T*ln2), T=0.5 */

#define NTILE  64                   /* 8192 / 128 row/col tiles */
#define CHUNK  5                    /* col-tiles per block-chunk */
#define NCHUNK 442                  /* sum_rt ceil((64-rt)/5) */
#define ROWSLOT0 64                 /* col-side slots 0..63 (=rt), row-side 64..76 */
#define NPARTS 77

typedef unsigned short ushort_t;
typedef __bf16 bf16x8 __attribute__((ext_vector_type(8)));
typedef float  f32x4  __attribute__((ext_vector_type(4)));

__device__ __forceinline__ ushort_t f2bf(float x) {
    union { float f; unsigned u; } a; a.f = x;
    unsigned r = a.u + 0x7fffu + ((a.u >> 16) & 1u);   /* RNE */
    return (ushort_t)(r >> 16);
}

__device__ __forceinline__ void gload_lds16(const void* g, void* l) {
    __builtin_amdgcn_global_load_lds(
        (const __attribute__((address_space(1))) unsigned int*)g,
        (__attribute__((address_space(3))) unsigned int*)l,
        16, 0, 0);
}

__global__ __launch_bounds__(256, 2) void k_mega(
        const float* __restrict__ feats, const float* __restrict__ tfeats,
        ushort_t* __restrict__ Xb, float* __restrict__ posv,
        float* __restrict__ parts, float* __restrict__ bsums,
        float* __restrict__ out) {
    __shared__ ushort_t lds[128 * 256];      /* 64 KB B/A staging */
    __shared__ float colred[4][128];         /* 2 KB cross-wave col-sum combine */
    __shared__ float red[4];

    cg::grid_group grid = cg::this_grid();
    const int t = threadIdx.x, l = t & 63, w = t >> 6;
    const int bid = blockIdx.x, nblk = gridDim.x;
    const int nwav = nblk * 4, gw = bid * 4 + w;

    /* ================= phase 1: normalize -> bf16 Xb; pos ================= */
    for (int row = gw; row < N_ROWS; row += nwav) {
        const float* src = (row < B_ROWS) ? feats + (size_t)row * DDIM
                                          : tfeats + (size_t)(row - B_ROWS) * DDIM;
        float4 v = ((const float4*)src)[l];
        float ss = v.x*v.x + v.y*v.y + v.z*v.z + v.w*v.w;
        #pragma unroll
        for (int m = 1; m < 64; m <<= 1) ss += __shfl_xor(ss, m);
        float inv = 1.0f / fmaxf(sqrtf(ss), 1e-12f);
        ushort4 o;
        o.x = f2bf(v.x * inv); o.y = f2bf(v.y * inv);
        o.z = f2bf(v.z * inv); o.w = f2bf(v.w * inv);
        ((ushort4*)(Xb + (size_t)row * DDIM))[l] = o;
    }
    for (int i = gw; i < B_ROWS; i += nwav) {
        float4 a = ((const float4*)(feats  + (size_t)i * DDIM))[l];
        float4 b = ((const float4*)(tfeats + (size_t)i * DDIM))[l];
        float d  = a.x*b.x + a.y*b.y + a.z*b.z + a.w*b.w;
        float sa = a.x*a.x + a.y*a.y + a.z*a.z + a.w*a.w;
        float sb = b.x*b.x + b.y*b.y + b.z*b.z + b.w*b.w;
        #pragma unroll
        for (int m = 1; m < 64; m <<= 1) {
            d += __shfl_xor(d, m); sa += __shfl_xor(sa, m); sb += __shfl_xor(sb, m);
        }
        if (l == 0) {
            float na = fmaxf(sqrtf(sa), 1e-12f), nb = fmaxf(sqrtf(sb), 1e-12f);
            posv[i] = d / (na * nb);
        }
    }
    __threadfence();
    grid.sync();

    /* ============ phase 2: A-resident triangular GEMM + exp-sums ========== */
    for (int c = bid; c < NCHUNK; c += nblk) {
        int rem = c, rt = 0;
        for (;;) {
            int ncc = (NTILE - rt + CHUNK - 1) / CHUNK;
            if (rem < ncc) break;
            rem -= ncc; ++rt;
        }
        const int cc = rem;
        const int rowbase = rt * 128;
        const int ct0 = rt + cc * CHUNK;
        int ctend = ct0 + CHUNK; if (ctend > NTILE) ctend = NTILE;

        /* ---- stage A panel [128][256] bf16 -> lds (swizzled) -> regs ---- */
        #pragma unroll
        for (int i = 0; i < 16; i++) {
            int o   = (t + i * 256) * 16;
            int row = o >> 9, cb = o & 511;
            int scb = cb ^ ((row & 7) << 4);
            gload_lds16((const char*)Xb + (size_t)(rowbase + row) * 512 + scb,
                        (char*)lds + o);
        }
        __syncthreads();
        bf16x8 af[2][8];
        #pragma unroll
        for (int m = 0; m < 2; m++) {
            int rowA = w * 32 + m * 16 + (l & 15);
            int sw = (rowA & 7) << 4;
            #pragma unroll
            for (int ks = 0; ks < 8; ks++) {
                int cb = ks * 64 + ((l >> 4) << 4);
                af[m][ks] = *(const bf16x8*)((const char*)lds + rowA * 512 + (cb ^ sw));
            }
        }
        __syncthreads();   /* all waves done reading A; lds free for B */

        float rs[2][4] = {{0.f,0.f,0.f,0.f},{0.f,0.f,0.f,0.f}};

        for (int ct = ct0; ct < ctend; ++ct) {
            const int colbase = ct * 128;
            const bool isdiag = (ct == rt);

            /* ---- stage B panel [128][256] bf16 ---- */
            #pragma unroll
            for (int i = 0; i < 16; i++) {
                int o   = (t + i * 256) * 16;
                int row = o >> 9, cb = o & 511;
                int scb = cb ^ ((row & 7) << 4);
                gload_lds16((const char*)Xb + (size_t)(colbase + row) * 512 + scb,
                            (char*)lds + o);
            }
            __syncthreads();

            /* ---- MFMA: wave w computes rows [w*32, w*32+32) x all 128 cols */
            f32x4 acc[2][8];
            #pragma unroll
            for (int m = 0; m < 2; m++)
                #pragma unroll
                for (int n = 0; n < 8; n++) acc[m][n] = (f32x4){0.f,0.f,0.f,0.f};

            #pragma unroll
            for (int ks = 0; ks < 8; ks++) {
                bf16x8 bfr[8];
                int cb = ks * 64 + ((l >> 4) << 4);
                #pragma unroll
                for (int n = 0; n < 8; n++) {
                    int rowB = n * 16 + (l & 15);
                    bfr[n] = *(const bf16x8*)((const char*)lds +
                                              rowB * 512 + (cb ^ ((rowB & 7) << 4)));
                }
                #pragma unroll
                for (int m = 0; m < 2; m++)
                    #pragma unroll
                    for (int n = 0; n < 8; n++)
                        acc[m][n] = __builtin_amdgcn_mfma_f32_16x16x32_bf16(
                            af[m][ks], bfr[n], acc[m][n], 0, 0, 0);
            }
            __syncthreads();   /* lds reads done; lds reusable next tile */

            /* ---- epilogue: e = exp2(sim*IT2), diag -> 1; rs/cs accum ---- */
            float cs[8] = {0.f,0.f,0.f,0.f,0.f,0.f,0.f,0.f};
            #pragma unroll
            for (int m = 0; m < 2; m++) {
                #pragma unroll
                for (int j = 0; j < 4; j++) {
                    int grow = rowbase + w * 32 + m * 16 + (l >> 4) * 4 + j;
                    #pragma unroll
                    for (int n = 0; n < 8; n++) {
                        int gcol = colbase + n * 16 + (l & 15);
                        float e = exp2f(acc[m][n][j] * IT2);
                        if (isdiag && grow == gcol) e = 1.0f;
                        rs[m][j] += e;
                        cs[n]    += e;
                    }
                }
            }

            /* col-side: combine 4 waves via LDS, write slot rt (skip diag) */
            if (!isdiag) {
                #pragma unroll
                for (int n = 0; n < 8; n++) {
                    float v = cs[n];
                    v += __shfl_xor(v, 16);
                    v += __shfl_xor(v, 32);
                    if (l < 16) colred[w][n * 16 + l] = v;
                }
            }
            __syncthreads();
            if (!isdiag && t < 128) {
                float s = colred[0][t] + colred[1][t] + colred[2][t] + colred[3][t];
                parts[(size_t)rt * N_ROWS + colbase + t] = s;
            }
            __syncthreads();   /* colred consumed before next tile reuses it */
        }

        /* row-side: reduce 16 col-lanes, write slot 64+cc */
        #pragma unroll
        for (int m = 0; m < 2; m++)
            #pragma unroll
            for (int j = 0; j < 4; j++) {
                float v = rs[m][j];
                v += __shfl_xor(v, 1); v += __shfl_xor(v, 2);
                v += __shfl_xor(v, 4); v += __shfl_xor(v, 8);
                if ((l & 15) == 0) {
                    int grow = rowbase + w * 32 + m * 16 + (l >> 4) * 4 + j;
                    parts[(size_t)(ROWSLOT0 + cc) * N_ROWS + grow] = v;
                }
            }
    }
    __threadfence();
    grid.sync();

    /* ========== phase 3: den -> log, + pos partials, block sums ========== */
    {
        float lsum = 0.0f;
        int tg = bid * 256 + t, nthr = nblk * 256;
        for (int row = tg; row < N_ROWS; row += nthr) {
            int rt = row >> 7;
            int ncc = (NTILE - rt + CHUNK - 1) / CHUNK;
            float den = 0.0f;
            for (int s = 0; s < rt; s++)
                den += parts[(size_t)s * N_ROWS + row];
            for (int ccs = 0; ccs < ncc; ccs++)
                den += parts[(size_t)(ROWSLOT0 + ccs) * N_ROWS + row];
            lsum += logf(den);
        }
        float psum = 0.0f;
        for (int i = tg; i < B_ROWS; i += nthr) psum += posv[i];
        /* total = sum(log den) - (1/T)*sum(pos); sum(pos)=2*sum(posv), 1/T=2 */
        float comb = lsum - 4.0f * psum;
        #pragma unroll
        for (int m = 1; m < 64; m <<= 1) comb += __shfl_xor(comb, m);
        if (l == 0) red[w] = comb;
        __syncthreads();
        if (t == 0) bsums[bid] = red[0] + red[1] + red[2] + red[3];
    }
    __threadfence();
    grid.sync();

    /* ========== phase 4: final scalar (block 0) ========== */
    if (bid == 0) {
        float v = 0.0f;
        for (int i = t; i < nblk; i += 256) v += bsums[i];
        #pragma unroll
        for (int m = 1; m < 64; m <<= 1) v += __shfl_xor(v, m);
        if (l == 0) red[w] = v;
        __syncthreads();
        if (t == 0) out[0] = (red[0] + red[1] + red[2] + red[3]) / (float)N_ROWS;
    }
}

extern "C" void kernel_launch(void* const* d_in, const int* in_sizes, int n_in,
                              void* d_out, int out_size, void* d_ws, size_t ws_size,
                              hipStream_t stream) {
    const float* feats  = (const float*)d_in[0];
    const float* tfeats = (const float*)d_in[1];
    float* out = (float*)d_out;
    char* ws = (char*)d_ws;

    ushort_t* Xb    = (ushort_t*)ws;                       /* 4 MB            */
    float*    posv  = (float*)(ws + 4194304);              /* 16 KB           */
    float*    parts = (float*)(ws + 4210688);              /* 77*8192*4 ~2.4MB*/
    float*    bsums = (float*)(ws + 6733824);              /* <= 8 KB         */

    int maxb = 0;
    hipError_t e = hipOccupancyMaxActiveBlocksPerMultiprocessor(&maxb, k_mega, 256, 0);
    if (e != hipSuccess || maxb < 1) maxb = 1;
    int grid = maxb * 256;                                 /* 256 CUs on MI355X */
    if (grid > 2048) grid = 2048;

    void* args[] = { (void*)&feats, (void*)&tfeats, (void*)&Xb, (void*)&posv,
                     (void*)&parts, (void*)&bsums, (void*)&out };
    hipLaunchCooperativeKernel((const void*)k_mega, dim3(grid), dim3(256),
                               args, 0, stream);
}

// Round 4
// 281.233 us; speedup vs baseline: 1.0256x; 1.0256x over previous
//
#include <hip/hip_runtime.h>
#include <hip/hip_cooperative_groups.h>

namespace cg = cooperative_groups;

#define B_ROWS 4096
#define N_ROWS 8192
#define DDIM   256
#define IT2    2.885390081777927f   /* 1/(T*ln2), T=0.5 */

#define NTILE   64                  /* 8192 / 128 */
#define NBLKTRI 2080                /* NTILE*(NTILE+1)/2 upper-tri tiles */
#define NPARTS  128                 /* 2 slots per tile-index, collision-free */

typedef unsigned short ushort_t;
typedef __bf16 bf16x8 __attribute__((ext_vector_type(8)));
typedef float  f32x4  __attribute__((ext_vector_type(4)));

__device__ __forceinline__ ushort_t f2bf(float x) {
    union { float f; unsigned u; } a; a.f = x;
    unsigned r = a.u + 0x7fffu + ((a.u >> 16) & 1u);   /* RNE */
    return (ushort_t)(r >> 16);
}

__device__ __forceinline__ void gload_lds16(const void* g, void* l) {
    __builtin_amdgcn_global_load_lds(
        (const __attribute__((address_space(1))) unsigned int*)g,
        (__attribute__((address_space(3))) unsigned int*)l,
        16, 0, 0);
}

__global__ __launch_bounds__(256) void k_mega(
        const float* __restrict__ feats, const float* __restrict__ tfeats,
        ushort_t* __restrict__ Xb, float* __restrict__ posv,
        float* __restrict__ parts, float* __restrict__ bsums,
        float* __restrict__ out) {
    __shared__ ushort_t ldsA[128 * 64];     /* 16 KB, swizzled content */
    __shared__ ushort_t ldsB[128 * 64];     /* 16 KB */
    __shared__ float red[4];

    cg::grid_group grid = cg::this_grid();
    const int t = threadIdx.x, l = t & 63, w = t >> 6;
    const int bid = blockIdx.x, nblk = gridDim.x;
    const int nwav = nblk * 4, gw = bid * 4 + w;

    /* ================ phase 1: normalize -> bf16 Xb; pos ================ */
    for (int row = gw; row < N_ROWS; row += nwav) {
        const float* src = (row < B_ROWS) ? feats + (size_t)row * DDIM
                                          : tfeats + (size_t)(row - B_ROWS) * DDIM;
        float4 v = ((const float4*)src)[l];
        float ss = v.x*v.x + v.y*v.y + v.z*v.z + v.w*v.w;
        #pragma unroll
        for (int m = 1; m < 64; m <<= 1) ss += __shfl_xor(ss, m);
        float inv = 1.0f / fmaxf(sqrtf(ss), 1e-12f);
        ushort4 o;
        o.x = f2bf(v.x * inv); o.y = f2bf(v.y * inv);
        o.z = f2bf(v.z * inv); o.w = f2bf(v.w * inv);
        ((ushort4*)(Xb + (size_t)row * DDIM))[l] = o;
    }
    for (int i = gw; i < B_ROWS; i += nwav) {
        float4 a = ((const float4*)(feats  + (size_t)i * DDIM))[l];
        float4 b = ((const float4*)(tfeats + (size_t)i * DDIM))[l];
        float d  = a.x*b.x + a.y*b.y + a.z*b.z + a.w*b.w;
        float sa = a.x*a.x + a.y*a.y + a.z*a.z + a.w*a.w;
        float sb = b.x*b.x + b.y*b.y + b.z*b.z + b.w*b.w;
        #pragma unroll
        for (int m = 1; m < 64; m <<= 1) {
            d += __shfl_xor(d, m); sa += __shfl_xor(sa, m); sb += __shfl_xor(sb, m);
        }
        if (l == 0) {
            float na = fmaxf(sqrtf(sa), 1e-12f), nb = fmaxf(sqrtf(sb), 1e-12f);
            posv[i] = d / (na * nb);
        }
    }
    __threadfence();
    grid.sync();

    /* ====== phase 2: triangular fused sim-GEMM + exp + row/col sums ===== */
    const int wm = w >> 1, wn = w & 1;
    for (int tile = bid; tile < NBLKTRI; tile += nblk) {
        int idx = tile, rt = 0;
        while (idx >= (NTILE - rt)) { idx -= (NTILE - rt); rt++; }
        const int ct = rt + idx;
        const bool isdiag = (rt == ct);
        const int rowbase = rt * 128;
        const int colbase = ct * 128;

        f32x4 acc[4][4];
        #pragma unroll
        for (int m = 0; m < 4; m++)
            #pragma unroll
            for (int n = 0; n < 4; n++) acc[m][n] = (f32x4){0.f, 0.f, 0.f, 0.f};

        for (int kb = 0; kb < DDIM; kb += 64) {
            /* stage A[128][64] and B[128][64] bf16; pre-swizzled source so
               the linear global_load_lds dest matches the XOR-swizzled read */
            #pragma unroll
            for (int i = 0; i < 4; i++) {
                int o   = (i * 256 + t) * 16;          /* byte off in 16 KB */
                int row = o >> 7;
                int cb  = o & 127;
                int scb = cb ^ ((row & 7) << 4);
                gload_lds16((const char*)Xb +
                            ((size_t)(rowbase + row) * DDIM + kb) * 2 + scb,
                            (char*)ldsA + o);
                gload_lds16((const char*)Xb +
                            ((size_t)(colbase + row) * DDIM + kb) * 2 + scb,
                            (char*)ldsB + o);
            }
            __syncthreads();

            #pragma unroll
            for (int ks = 0; ks < 2; ks++) {
                bf16x8 af[4], bfr[4];
                int cbw = ((l >> 4) * 16) + ks * 64;
                #pragma unroll
                for (int m = 0; m < 4; m++) {
                    int row  = wm * 64 + m * 16 + (l & 15);
                    int addr = row * 128 + (cbw ^ ((row & 7) << 4));
                    af[m] = *(const bf16x8*)((const char*)ldsA + addr);
                }
                #pragma unroll
                for (int n = 0; n < 4; n++) {
                    int row  = wn * 64 + n * 16 + (l & 15);
                    int addr = row * 128 + (cbw ^ ((row & 7) << 4));
                    bfr[n] = *(const bf16x8*)((const char*)ldsB + addr);
                }
                #pragma unroll
                for (int m = 0; m < 4; m++)
                    #pragma unroll
                    for (int n = 0; n < 4; n++)
                        acc[m][n] = __builtin_amdgcn_mfma_f32_16x16x32_bf16(
                            af[m], bfr[n], acc[m][n], 0, 0, 0);
            }
            __syncthreads();
        }

        /* epilogue: e = exp2(sim*IT2); diag tile -> 1.0 on the diagonal */
        float rs[4][4];
        float cs[4] = {0.f, 0.f, 0.f, 0.f};
        #pragma unroll
        for (int m = 0; m < 4; m++)
            #pragma unroll
            for (int j = 0; j < 4; j++) rs[m][j] = 0.0f;

        #pragma unroll
        for (int m = 0; m < 4; m++) {
            #pragma unroll
            for (int j = 0; j < 4; j++) {
                int grow = rowbase + wm * 64 + m * 16 + (l >> 4) * 4 + j;
                #pragma unroll
                for (int n = 0; n < 4; n++) {
                    int gcol = colbase + wn * 64 + n * 16 + (l & 15);
                    float e = exp2f(acc[m][n][j] * IT2);
                    if (isdiag && grow == gcol) e = 1.0f;
                    rs[m][j] += e;
                    cs[n]    += e;
                }
            }
        }

        /* row sums: reduce lanes 0-15 (columns), slot ct*2+wn */
        #pragma unroll
        for (int m = 0; m < 4; m++)
            #pragma unroll
            for (int j = 0; j < 4; j++) {
                float v = rs[m][j];
                v += __shfl_xor(v, 1); v += __shfl_xor(v, 2);
                v += __shfl_xor(v, 4); v += __shfl_xor(v, 8);
                if ((l & 15) == 0) {
                    int grow = rowbase + wm * 64 + m * 16 + (l >> 4) * 4 + j;
                    parts[(size_t)(ct * 2 + wn) * N_ROWS + grow] = v;
                }
            }

        /* col sums: reduce lane-groups (rows), slot rt*2+wm */
        if (!isdiag) {
            #pragma unroll
            for (int n = 0; n < 4; n++) {
                float v = cs[n];
                v += __shfl_xor(v, 16);
                v += __shfl_xor(v, 32);
                if (l < 16) {
                    int gcol = colbase + wn * 64 + n * 16 + l;
                    parts[(size_t)(rt * 2 + wm) * N_ROWS + gcol] = v;
                }
            }
        }
    }
    __threadfence();
    grid.sync();

    /* ====== phase 3: den -> log, + pos partials, per-block sums ========= */
    {
        float lsum = 0.0f;
        int tg = bid * 256 + t, nthr = nblk * 256;
        for (int row = tg; row < N_ROWS; row += nthr) {
            float den = 0.0f;
            #pragma unroll 8
            for (int p = 0; p < NPARTS; p++) den += parts[(size_t)p * N_ROWS + row];
            lsum += logf(den);
        }
        float psum = 0.0f;
        for (int i = tg; i < B_ROWS; i += nthr) psum += posv[i];
        /* total = sum(log den) - (1/T)*sum(pos); sum(pos)=2*sum(posv), 1/T=2 */
        float comb = lsum - 4.0f * psum;
        #pragma unroll
        for (int m = 1; m < 64; m <<= 1) comb += __shfl_xor(comb, m);
        if (l == 0) red[w] = comb;
        __syncthreads();
        if (t == 0) bsums[bid] = red[0] + red[1] + red[2] + red[3];
    }
    __threadfence();
    grid.sync();

    /* ====== phase 4: final scalar (block 0) ============================= */
    if (bid == 0) {
        float v = 0.0f;
        for (int i = t; i < nblk; i += 256) v += bsums[i];
        #pragma unroll
        for (int m = 1; m < 64; m <<= 1) v += __shfl_xor(v, m);
        if (l == 0) red[w] = v;
        __syncthreads();
        if (t == 0) out[0] = (red[0] + red[1] + red[2] + red[3]) / (float)N_ROWS;
    }
}

extern "C" void kernel_launch(void* const* d_in, const int* in_sizes, int n_in,
                              void* d_out, int out_size, void* d_ws, size_t ws_size,
                              hipStream_t stream) {
    const float* feats  = (const float*)d_in[0];
    const float* tfeats = (const float*)d_in[1];
    float* out = (float*)d_out;
    char* ws = (char*)d_ws;

    ushort_t* Xb    = (ushort_t*)ws;                       /* 4 MB            */
    float*    posv  = (float*)(ws + 4194304);              /* 16 KB           */
    float*    parts = (float*)(ws + 4210688);              /* 128*8192*4=4 MB */
    float*    bsums = (float*)(ws + 8404992);              /* <= 8 KB         */

    int maxb = 0;
    hipError_t e = hipOccupancyMaxActiveBlocksPerMultiprocessor(&maxb, k_mega, 256, 0);
    if (e != hipSuccess || maxb < 1) maxb = 1;
    int grid = maxb * 256;                                 /* 256 CUs */
    if (grid > 2048) grid = 2048;

    void* args[] = { (void*)&feats, (void*)&tfeats, (void*)&Xb, (void*)&posv,
                     (void*)&parts, (void*)&bsums, (void*)&out };
    hipLaunchCooperativeKernel((const void*)k_mega, dim3(grid), dim3(256),
                               args, 0, stream);
}

// Round 5
// 235.935 us; speedup vs baseline: 1.2225x; 1.1920x over previous
//
#include <hip/hip_runtime.h>

#define B_ROWS 4096
#define N_ROWS 8192
#define DDIM   256
#define IT2    2.885390081777927f   /* 1/(T*ln2), T=0.5 */

#define NTILE   64                  /* 8192 / 128 */
#define NBLKTRI 2080                /* NTILE*(NTILE+1)/2 upper-tri tiles */

typedef unsigned short ushort_t;
typedef __bf16 bf16x8 __attribute__((ext_vector_type(8)));
typedef float  f32x4  __attribute__((ext_vector_type(4)));

__device__ __forceinline__ ushort_t f2bf(float x) {
    union { float f; unsigned u; } a; a.f = x;
    unsigned r = a.u + 0x7fffu + ((a.u >> 16) & 1u);   /* RNE */
    return (ushort_t)(r >> 16);
}

__device__ __forceinline__ void gload_lds16(const void* g, void* l) {
    __builtin_amdgcn_global_load_lds(
        (const __attribute__((address_space(1))) unsigned int*)g,
        (__attribute__((address_space(3))) unsigned int*)l,
        16, 0, 0);
}

/* ---- kernel A: normalize -> bf16 Xb; pos; zero den/ticket -------------- */
__global__ __launch_bounds__(256) void k_prep(
        const float* __restrict__ feats, const float* __restrict__ tfeats,
        ushort_t* __restrict__ Xb, float* __restrict__ posv,
        float* __restrict__ den4, int* __restrict__ ticket) {
    __shared__ float fbuf[2][DDIM];
    __shared__ float nsh[4];
    int w = threadIdx.x >> 6, l = threadIdx.x & 63;
    int bid = blockIdx.x;
    int i0 = bid * 2;                                /* grid 2048 */

    /* zero-init den4[4][8192] + ticket (ws is poisoned 0xAA) */
    int z = bid * 256 + threadIdx.x;
    if (z < 4 * N_ROWS) den4[z] = 0.0f;
    if (z == 4 * N_ROWS) *ticket = 0;

    int pair = (w < 2) ? w : (w - 2);
    int row  = (w < 2) ? (i0 + pair) : (i0 + pair + B_ROWS);
    const float* src = (w < 2) ? feats + (size_t)(i0 + pair) * DDIM
                               : tfeats + (size_t)(i0 + pair) * DDIM;
    float4 v = ((const float4*)src)[l];
    float ss = v.x*v.x + v.y*v.y + v.z*v.z + v.w*v.w;
    #pragma unroll
    for (int m = 1; m < 64; m <<= 1) ss += __shfl_xor(ss, m);
    float nrm = fmaxf(sqrtf(ss), 1e-12f);
    float inv = 1.0f / nrm;
    ushort4 o;
    o.x = f2bf(v.x * inv); o.y = f2bf(v.y * inv);
    o.z = f2bf(v.z * inv); o.w = f2bf(v.w * inv);
    ((ushort4*)(Xb + (size_t)row * DDIM))[l] = o;
    if (w < 2) ((float4*)fbuf[pair])[l] = v;
    if (l == 0) nsh[w] = nrm;
    __syncthreads();
    if (w >= 2) {
        float4 a = ((const float4*)fbuf[pair])[l];
        float d = a.x*v.x + a.y*v.y + a.z*v.z + a.w*v.w;
        #pragma unroll
        for (int m = 1; m < 64; m <<= 1) d += __shfl_xor(d, m);
        if (l == 0) posv[i0 + pair] = d / (nsh[pair] * nsh[w]);
    }
}

/* ---- kernel B: dbuf triangular GEMM + exp + atomic den; last-block tail */
__global__ __launch_bounds__(256) void k_main(
        const ushort_t* __restrict__ Xb, const float* __restrict__ posv,
        float* __restrict__ den4, int* __restrict__ ticket,
        float* __restrict__ out) {
    __shared__ ushort_t lds[2][2][128 * 64];   /* [buf][A/B][tile] = 64 KB */
    __shared__ float red[4];
    __shared__ int islast;

    const int t = threadIdx.x, l = t & 63, w = t >> 6;
    const int wm = w >> 1, wn = w & 1;

    /* blockIdx -> upper-triangle tile (rt, ct), rt <= ct */
    int idx = blockIdx.x, rt = 0;
    while (idx >= (NTILE - rt)) { idx -= (NTILE - rt); rt++; }
    const int ct = rt + idx;
    const bool isdiag = (rt == ct);
    const int rowbase = rt * 128;
    const int colbase = ct * 128;

    /* stage A[128][64] and B[128][64] bf16 of K-step kb into lds[buf];
       pre-swizzled source so linear gload_lds dest == XOR-swizzled read */
    #define STAGE(buf, kb)                                                   \
        do {                                                                 \
            _Pragma("unroll")                                                \
            for (int i = 0; i < 4; i++) {                                    \
                int o   = (i * 256 + t) * 16;                                \
                int row = o >> 7;                                            \
                int cb  = o & 127;                                           \
                int scb = cb ^ ((row & 7) << 4);                             \
                gload_lds16((const char*)Xb +                                \
                    ((size_t)(rowbase + row) * DDIM + (kb) * 64) * 2 + scb,  \
                    (char*)lds[buf][0] + o);                                 \
                gload_lds16((const char*)Xb +                                \
                    ((size_t)(colbase + row) * DDIM + (kb) * 64) * 2 + scb,  \
                    (char*)lds[buf][1] + o);                                 \
            }                                                                \
        } while (0)

    f32x4 acc[4][4];
    #pragma unroll
    for (int m = 0; m < 4; m++)
        #pragma unroll
        for (int n = 0; n < 4; n++) acc[m][n] = (f32x4){0.f, 0.f, 0.f, 0.f};

    STAGE(0, 0);
    __syncthreads();                 /* buf0 ready (full drain) */

    #pragma unroll
    for (int kb = 0; kb < 4; kb++) {
        const int buf = kb & 1;
        if (kb < 3) STAGE(buf ^ 1, kb + 1);   /* issue next; hides under MFMA */

        #pragma unroll
        for (int ks = 0; ks < 2; ks++) {
            bf16x8 af[4], bfr[4];
            int cbw = ((l >> 4) * 16) + ks * 64;
            #pragma unroll
            for (int m = 0; m < 4; m++) {
                int row  = wm * 64 + m * 16 + (l & 15);
                int addr = row * 128 + (cbw ^ ((row & 7) << 4));
                af[m] = *(const bf16x8*)((const char*)lds[buf][0] + addr);
            }
            #pragma unroll
            for (int n = 0; n < 4; n++) {
                int row  = wn * 64 + n * 16 + (l & 15);
                int addr = row * 128 + (cbw ^ ((row & 7) << 4));
                bfr[n] = *(const bf16x8*)((const char*)lds[buf][1] + addr);
            }
            #pragma unroll
            for (int m = 0; m < 4; m++)
                #pragma unroll
                for (int n = 0; n < 4; n++)
                    acc[m][n] = __builtin_amdgcn_mfma_f32_16x16x32_bf16(
                        af[m], bfr[n], acc[m][n], 0, 0, 0);
        }
        __syncthreads();             /* drains vmcnt: next buf ready; guards reuse */
    }

    /* epilogue: e = exp2(sim*IT2); diag tile -> 1.0 on the diagonal */
    float rs[4][4];
    float cs[4] = {0.f, 0.f, 0.f, 0.f};
    #pragma unroll
    for (int m = 0; m < 4; m++)
        #pragma unroll
        for (int j = 0; j < 4; j++) rs[m][j] = 0.0f;

    #pragma unroll
    for (int m = 0; m < 4; m++) {
        #pragma unroll
        for (int j = 0; j < 4; j++) {
            int grow = rowbase + wm * 64 + m * 16 + (l >> 4) * 4 + j;
            #pragma unroll
            for (int n = 0; n < 4; n++) {
                int gcol = colbase + wn * 64 + n * 16 + (l & 15);
                float e = exp2f(acc[m][n][j] * IT2);
                if (isdiag && grow == gcol) e = 1.0f;
                rs[m][j] += e;
                cs[n]    += e;
            }
        }
    }

    /* row sums -> den4[wn]; col sums -> den4[2+wm] (fire-and-forget) */
    #pragma unroll
    for (int m = 0; m < 4; m++)
        #pragma unroll
        for (int j = 0; j < 4; j++) {
            float v = rs[m][j];
            v += __shfl_xor(v, 1); v += __shfl_xor(v, 2);
            v += __shfl_xor(v, 4); v += __shfl_xor(v, 8);
            if ((l & 15) == 0) {
                int grow = rowbase + wm * 64 + m * 16 + (l >> 4) * 4 + j;
                atomicAdd(&den4[(size_t)wn * N_ROWS + grow], v);
            }
        }
    if (!isdiag) {
        #pragma unroll
        for (int n = 0; n < 4; n++) {
            float v = cs[n];
            v += __shfl_xor(v, 16);
            v += __shfl_xor(v, 32);
            if (l < 16) {
                int gcol = colbase + wn * 64 + n * 16 + l;
                atomicAdd(&den4[(size_t)(2 + wm) * N_ROWS + gcol], v);
            }
        }
    }

    /* ---- ticket: last block to finish computes the scalar tail ---------- */
    __threadfence();                           /* release den atomics        */
    if (t == 0) islast = (atomicAdd(ticket, 1) == NBLKTRI - 1);
    __syncthreads();
    if (!islast) return;

    float lsum = 0.0f;
    for (int r = t; r < N_ROWS; r += 256) {
        float d = 0.0f;
        #pragma unroll
        for (int s = 0; s < 4; s++)
            d += __hip_atomic_load(&den4[(size_t)s * N_ROWS + r],
                                   __ATOMIC_RELAXED, __HIP_MEMORY_SCOPE_AGENT);
        lsum += logf(d);
    }
    float psum = 0.0f;
    for (int i = t; i < B_ROWS; i += 256) psum += posv[i];
    /* total = sum(log den) - (1/T)*sum(pos); sum(pos)=2*sum(posv), 1/T=2 */
    float comb = lsum - 4.0f * psum;
    #pragma unroll
    for (int m = 1; m < 64; m <<= 1) comb += __shfl_xor(comb, m);
    if (l == 0) red[w] = comb;
    __syncthreads();
    if (t == 0) out[0] = (red[0] + red[1] + red[2] + red[3]) / (float)N_ROWS;
}

extern "C" void kernel_launch(void* const* d_in, const int* in_sizes, int n_in,
                              void* d_out, int out_size, void* d_ws, size_t ws_size,
                              hipStream_t stream) {
    const float* feats  = (const float*)d_in[0];
    const float* tfeats = (const float*)d_in[1];
    float* out = (float*)d_out;
    char* ws = (char*)d_ws;

    ushort_t* Xb     = (ushort_t*)ws;                   /* 4 MB              */
    float*    posv   = (float*)(ws + 4194304);          /* 16 KB             */
    float*    den4   = (float*)(ws + 4210688);          /* 4*8192*4 = 128 KB */
    int*      ticket = (int*)(ws + 4341760);            /* 4 B               */

    k_prep<<<B_ROWS / 2, 256, 0, stream>>>(feats, tfeats, Xb, posv, den4, ticket);
    k_main<<<NBLKTRI, 256, 0, stream>>>(Xb, posv, den4, ticket, out);
}

// Round 6
// 189.508 us; speedup vs baseline: 1.5221x; 1.2450x over previous
//
#include <hip/hip_runtime.h>

#define B_ROWS 4096
#define N_ROWS 8192
#define DDIM   256
#define IT2    2.885390081777927f   /* 1/(T*ln2), T=0.5 */

#define NTILE   64                  /* 8192 / 128 */
#define NCHUNK2 1056                /* sum_rt ceil((64-rt)/2) */

typedef unsigned short ushort_t;
typedef __bf16 bf16x8 __attribute__((ext_vector_type(8)));
typedef float  f32x4  __attribute__((ext_vector_type(4)));

__device__ __forceinline__ ushort_t f2bf(float x) {
    union { float f; unsigned u; } a; a.f = x;
    unsigned r = a.u + 0x7fffu + ((a.u >> 16) & 1u);   /* RNE */
    return (ushort_t)(r >> 16);
}

__device__ __forceinline__ void gload_lds16(const void* g, void* l) {
    __builtin_amdgcn_global_load_lds(
        (const __attribute__((address_space(1))) unsigned int*)g,
        (__attribute__((address_space(3))) unsigned int*)l,
        16, 0, 0);
}

/* ---- kernel A: normalize -> bf16 Xb; pos; zero den/ticket -------------- */
__global__ __launch_bounds__(256) void k_prep(
        const float* __restrict__ feats, const float* __restrict__ tfeats,
        ushort_t* __restrict__ Xb, float* __restrict__ posv,
        float* __restrict__ den4, int* __restrict__ ticket) {
    __shared__ float fbuf[2][DDIM];
    __shared__ float nsh[4];
    int w = threadIdx.x >> 6, l = threadIdx.x & 63;
    int bid = blockIdx.x;
    int i0 = bid * 2;                                /* grid 2048 */

    /* zero-init den4[4][8192] + ticket (ws is poisoned 0xAA) */
    int z = bid * 256 + threadIdx.x;
    if (z < 4 * N_ROWS) den4[z] = 0.0f;
    if (z == 4 * N_ROWS) *ticket = 0;

    int pair = (w < 2) ? w : (w - 2);
    int row  = (w < 2) ? (i0 + pair) : (i0 + pair + B_ROWS);
    const float* src = (w < 2) ? feats + (size_t)(i0 + pair) * DDIM
                               : tfeats + (size_t)(i0 + pair) * DDIM;
    float4 v = ((const float4*)src)[l];
    float ss = v.x*v.x + v.y*v.y + v.z*v.z + v.w*v.w;
    #pragma unroll
    for (int m = 1; m < 64; m <<= 1) ss += __shfl_xor(ss, m);
    float nrm = fmaxf(sqrtf(ss), 1e-12f);
    float inv = 1.0f / nrm;
    ushort4 o;
    o.x = f2bf(v.x * inv); o.y = f2bf(v.y * inv);
    o.z = f2bf(v.z * inv); o.w = f2bf(v.w * inv);
    ((ushort4*)(Xb + (size_t)row * DDIM))[l] = o;
    if (w < 2) ((float4*)fbuf[pair])[l] = v;
    if (l == 0) nsh[w] = nrm;
    __syncthreads();
    if (w >= 2) {
        float4 a = ((const float4*)fbuf[pair])[l];
        float d = a.x*v.x + a.y*v.y + a.z*v.z + a.w*v.w;
        #pragma unroll
        for (int m = 1; m < 64; m <<= 1) d += __shfl_xor(d, m);
        if (l == 0) posv[i0 + pair] = d / (nsh[pair] * nsh[w]);
    }
}

/* ---- kernel B: triangular chunked GEMM + exp + atomic den; ticket tail - */
__global__ __launch_bounds__(256) void k_main(
        const ushort_t* __restrict__ Xb, const float* __restrict__ posv,
        float* __restrict__ den4, int* __restrict__ ticket,
        float* __restrict__ out) {
    __shared__ ushort_t ldsA[128 * 64];     /* 16 KB, swizzled content */
    __shared__ ushort_t ldsB[128 * 64];     /* 16 KB */
    __shared__ float red[4];
    __shared__ int islast;

    const int t = threadIdx.x, l = t & 63, w = t >> 6;
    const int wm = w >> 1, wn = w & 1;

    /* blockIdx -> (rt, chunk cc of 2 col-tiles), upper triangle */
    int idx = blockIdx.x, rt = 0;
    for (;;) {
        int nc = (NTILE - rt + 1) >> 1;     /* ceil((64-rt)/2) */
        if (idx < nc) break;
        idx -= nc; rt++;
    }
    const int rowbase = rt * 128;
    const int ct0 = rt + idx * 2;
    const int ctend = (ct0 + 2 <= NTILE) ? ct0 + 2 : NTILE;

    /* row sums accumulate across the chunk */
    float rs[4][4];
    #pragma unroll
    for (int m = 0; m < 4; m++)
        #pragma unroll
        for (int j = 0; j < 4; j++) rs[m][j] = 0.0f;

    for (int ct = ct0; ct < ctend; ++ct) {
        const bool isdiag = (ct == rt);
        const int colbase = ct * 128;

        f32x4 acc[4][4];
        #pragma unroll
        for (int m = 0; m < 4; m++)
            #pragma unroll
            for (int n = 0; n < 4; n++) acc[m][n] = (f32x4){0.f, 0.f, 0.f, 0.f};

        for (int kb = 0; kb < DDIM; kb += 64) {
            /* stage A[128][64], B[128][64]; pre-swizzled source so the
               linear global_load_lds dest matches the XOR-swizzled read */
            #pragma unroll
            for (int i = 0; i < 4; i++) {
                int o   = (i * 256 + t) * 16;
                int row = o >> 7;
                int cb  = o & 127;
                int scb = cb ^ ((row & 7) << 4);
                gload_lds16((const char*)Xb +
                            ((size_t)(rowbase + row) * DDIM + kb) * 2 + scb,
                            (char*)ldsA + o);
                gload_lds16((const char*)Xb +
                            ((size_t)(colbase + row) * DDIM + kb) * 2 + scb,
                            (char*)ldsB + o);
            }
            __syncthreads();

            #pragma unroll
            for (int ks = 0; ks < 2; ks++) {
                bf16x8 af[4], bfr[4];
                int cbw = ((l >> 4) * 16) + ks * 64;
                #pragma unroll
                for (int m = 0; m < 4; m++) {
                    int row  = wm * 64 + m * 16 + (l & 15);
                    int addr = row * 128 + (cbw ^ ((row & 7) << 4));
                    af[m] = *(const bf16x8*)((const char*)ldsA + addr);
                }
                #pragma unroll
                for (int n = 0; n < 4; n++) {
                    int row  = wn * 64 + n * 16 + (l & 15);
                    int addr = row * 128 + (cbw ^ ((row & 7) << 4));
                    bfr[n] = *(const bf16x8*)((const char*)ldsB + addr);
                }
                #pragma unroll
                for (int m = 0; m < 4; m++)
                    #pragma unroll
                    for (int n = 0; n < 4; n++)
                        acc[m][n] = __builtin_amdgcn_mfma_f32_16x16x32_bf16(
                            af[m], bfr[n], acc[m][n], 0, 0, 0);
            }
            __syncthreads();
        }

        /* epilogue: e = exp2(sim*IT2); diag tile -> 1.0 on the diagonal */
        float cs[4] = {0.f, 0.f, 0.f, 0.f};
        #pragma unroll
        for (int m = 0; m < 4; m++) {
            #pragma unroll
            for (int j = 0; j < 4; j++) {
                int grow = rowbase + wm * 64 + m * 16 + (l >> 4) * 4 + j;
                #pragma unroll
                for (int n = 0; n < 4; n++) {
                    int gcol = colbase + wn * 64 + n * 16 + (l & 15);
                    float e = exp2f(acc[m][n][j] * IT2);
                    if (isdiag && grow == gcol) e = 1.0f;
                    rs[m][j] += e;
                    cs[n]    += e;
                }
            }
        }

        /* col sums -> den4[2+wm] (fire-and-forget, per ct) */
        if (!isdiag) {
            #pragma unroll
            for (int n = 0; n < 4; n++) {
                float v = cs[n];
                v += __shfl_xor(v, 16);
                v += __shfl_xor(v, 32);
                if (l < 16) {
                    int gcol = colbase + wn * 64 + n * 16 + l;
                    atomicAdd(&den4[(size_t)(2 + wm) * N_ROWS + gcol], v);
                }
            }
        }
    }

    /* row sums -> den4[wn] (once per block, accumulated over chunk) */
    #pragma unroll
    for (int m = 0; m < 4; m++)
        #pragma unroll
        for (int j = 0; j < 4; j++) {
            float v = rs[m][j];
            v += __shfl_xor(v, 1); v += __shfl_xor(v, 2);
            v += __shfl_xor(v, 4); v += __shfl_xor(v, 8);
            if ((l & 15) == 0) {
                int grow = rowbase + wm * 64 + m * 16 + (l >> 4) * 4 + j;
                atomicAdd(&den4[(size_t)wn * N_ROWS + grow], v);
            }
        }

    /* ---- ticket: last block to finish computes the scalar tail --------- */
    __threadfence();
    if (t == 0) islast = (atomicAdd(ticket, 1) == NCHUNK2 - 1);
    __syncthreads();
    if (!islast) return;

    float lsum = 0.0f;
    for (int r = t; r < N_ROWS; r += 256) {
        float d = 0.0f;
        #pragma unroll
        for (int s = 0; s < 4; s++)
            d += __hip_atomic_load(&den4[(size_t)s * N_ROWS + r],
                                   __ATOMIC_RELAXED, __HIP_MEMORY_SCOPE_AGENT);
        lsum += logf(d);
    }
    float psum = 0.0f;
    for (int i = t; i < B_ROWS; i += 256) psum += posv[i];
    /* total = sum(log den) - (1/T)*sum(pos); sum(pos)=2*sum(posv), 1/T=2 */
    float comb = lsum - 4.0f * psum;
    #pragma unroll
    for (int m = 1; m < 64; m <<= 1) comb += __shfl_xor(comb, m);
    if (l == 0) red[w] = comb;
    __syncthreads();
    if (t == 0) out[0] = (red[0] + red[1] + red[2] + red[3]) / (float)N_ROWS;
}

extern "C" void kernel_launch(void* const* d_in, const int* in_sizes, int n_in,
                              void* d_out, int out_size, void* d_ws, size_t ws_size,
                              hipStream_t stream) {
    const float* feats  = (const float*)d_in[0];
    const float* tfeats = (const float*)d_in[1];
    float* out = (float*)d_out;
    char* ws = (char*)d_ws;

    ushort_t* Xb     = (ushort_t*)ws;                   /* 4 MB              */
    float*    posv   = (float*)(ws + 4194304);          /* 16 KB             */
    float*    den4   = (float*)(ws + 4210688);          /* 4*8192*4 = 128 KB */
    int*      ticket = (int*)(ws + 4341760);            /* 4 B               */

    k_prep<<<B_ROWS / 2, 256, 0, stream>>>(feats, tfeats, Xb, posv, den4, ticket);
    k_main<<<NCHUNK2, 256, 0, stream>>>(Xb, posv, den4, ticket, out);
}